// Round 20
// baseline (686.000 us; speedup 1.0000x reference)
//
#include <hip/hip_runtime.h>
#include <hip/hip_fp16.h>
#include <math.h>

#define B_  32
#define N_  512
#define H_  128
#define E_  131072
#define T_  9
#define BN_ (B_*N_)
#define EPB 64   // edges per block in edge MFMA GEMM

typedef unsigned short ushort_t;
typedef __attribute__((ext_vector_type(8))) _Float16 f16x8;
typedef __attribute__((ext_vector_type(8))) unsigned short ushort8;
typedef __attribute__((ext_vector_type(4))) float f32x4;

// 128-k-row swizzle for B LDS tiles: XOR 32-chunk bits and 16B-slot bits with
// row bits -> low-way LDS bank access for ds_read_b128 at 256B row stride.
__device__ __forceinline__ int kswz128(int k, int n) {
    int kc = ((k >> 5) ^ (n >> 3)) & 3;
    int sp = ((k >> 3) ^ (n >> 1)) & 3;
    return (kc << 5) | (sp << 3) | (k & 7);
}
// logical k-offset feeding phys 16B slot s of (local) row (A-plane source swizzle)
__device__ __forceinline__ int aslot_src(int s, int row) {
    int kc = ((s >> 2) ^ (row >> 3)) & 3;
    int kg = ((s & 3) ^ (row >> 1)) & 3;
    return (kc << 5) + (kg << 3);
}
// LDS ushort offset for (local row, logical 32-chunk kc, 8-elem group g)
__device__ __forceinline__ int ldoff(int row, int kc, int g) {
    return row * 128 + (((kc ^ (row >> 3)) & 3) << 5) + (((g ^ (row >> 1)) & 3) << 3);
}

// meta layout (ints): [0..8]=cnt, [9..17]=start, [18..26]=off(atomic), [27..36]=cumBlocks(10)

// ---------------- fused histograms (type + target) ----------------
__global__ void count_all(const int* __restrict__ eids, int* __restrict__ meta,
                          int* __restrict__ tcnt) {
    __shared__ int lc[T_];
    if (threadIdx.x < T_) lc[threadIdx.x] = 0;
    __syncthreads();
    int e = blockIdx.x * 256 + threadIdx.x;
    if (e < E_) {
        int4 v = reinterpret_cast<const int4*>(eids)[e];
        atomicAdd(&lc[v.x], 1);
        atomicAdd(&tcnt[v.y * N_ + v.w], 1);
    }
    __syncthreads();
    if (threadIdx.x < T_ && lc[threadIdx.x]) atomicAdd(&meta[threadIdx.x], lc[threadIdx.x]);
}

// target scan + tiny type scan
__global__ void scan_all(const int* __restrict__ tcnt, int* __restrict__ tstart,
                         int* __restrict__ toff, int* __restrict__ meta) {
    __shared__ int bs[256];
    const int tid = threadIdx.x;
    if (tid == 0) {
        int s = 0;
        for (int t = 0; t < T_; ++t) { meta[9 + t] = s; meta[18 + t] = s; s += meta[t]; }
        int cb = 0;
        for (int t = 0; t < T_; ++t) { meta[27 + t] = cb; cb += (meta[t] + EPB - 1) / EPB; }
        meta[27 + T_] = cb;
    }
    const int chunk = BN_ / 256;   // 64
    const int base = tid * chunk;
    int s = 0;
    for (int i = 0; i < chunk; ++i) s += tcnt[base + i];
    bs[tid] = s;
    __syncthreads();
    if (tid == 0) { int acc = 0; for (int i = 0; i < 256; ++i) { int v = bs[i]; bs[i] = acc; acc += v; } }
    __syncthreads();
    int acc = bs[tid];
    for (int i = 0; i < chunk; ++i) {
        int v = tcnt[base + i];
        tstart[base + i] = acc; toff[base + i] = acc; acc += v;
    }
    if (tid == 255) tstart[BN_] = E_;
}

// ---------------- fused scatter (type perm + target rank) ----------------
__global__ void scatter_all(const int* __restrict__ eids, int* __restrict__ meta,
                            int* __restrict__ toff, int* __restrict__ perm,
                            int* __restrict__ rank) {
    __shared__ int lc[T_], lbase[T_];
    if (threadIdx.x < T_) lc[threadIdx.x] = 0;
    __syncthreads();
    int e = blockIdx.x * 256 + threadIdx.x;
    int4 v = {0, 0, 0, 0};
    int lp = 0;
    if (e < E_) { v = reinterpret_cast<const int4*>(eids)[e]; lp = atomicAdd(&lc[v.x], 1); }
    __syncthreads();
    if (threadIdx.x < T_ && lc[threadIdx.x])
        lbase[threadIdx.x] = atomicAdd(&meta[18 + threadIdx.x], lc[threadIdx.x]);
    __syncthreads();
    if (e < E_) {
        perm[lbase[v.x] + lp] = e;
        rank[e] = atomicAdd(&toff[v.y * N_ + v.w], 1);
    }
}

// ---------------- state cast: fp32 (BN,H) -> fp16 plane ----------------
__global__ __launch_bounds__(256) void cast_state(const float* __restrict__ in,
                                                  ushort_t* __restrict__ hP) {
    int i = blockIdx.x * 256 + threadIdx.x;      // over BN*H/4
    float4 v = reinterpret_cast<const float4*>(in)[i];
    ushort4 h;
    h.x = __builtin_bit_cast(ushort_t, __float2half(v.x));
    h.y = __builtin_bit_cast(ushort_t, __float2half(v.y));
    h.z = __builtin_bit_cast(ushort_t, __float2half(v.z));
    h.w = __builtin_bit_cast(ushort_t, __float2half(v.w));
    reinterpret_cast<ushort4*>(hP)[i] = h;
}

// ---------------- weight fp16 transpose for edge MFMA (all layers) ----------------
// in: (4,T,H,H) = W[l][t][k][n]; out: (4,T,128,128) = [lt][n][kswz128(k,n)] fp16
__global__ void build_wt(const float* __restrict__ W, ushort_t* __restrict__ wt16) {
    int idx = blockIdx.x * 256 + threadIdx.x;
    if (idx >= 4 * T_ * H_ * H_) return;
    int lt = idx / (H_ * H_);
    int rem = idx - lt * H_ * H_;
    int n = rem >> 7, k = rem & 127;
    float v = W[(size_t)lt * H_ * H_ + k * H_ + n];
    size_t o = (size_t)lt * H_ * H_ + n * 128 + kswz128(k, n);
    wt16[o] = __builtin_bit_cast(ushort_t, __float2half(v));
}

// ---------------- B2 build: gate-interleaved padded GRU weights ----------------
// Row n' = cg*128 + gate*32 + c covers gate column j = cg*32 + c; every gate
// zero-padded to span [0,K). gate: 0=z 1=r 2=xh 3=hh.
struct BtArgs {
    const float* W[4];
    const float* U[4];
    unsigned long long off[4];
    int K[4];
};
__global__ void build_bt2(BtArgs a, ushort_t* __restrict__ bt16) {
    const int lyr = blockIdx.y;
    const int K = a.K[lyr];
    const int Kx = K - 128;
    int idx = blockIdx.x * 256 + threadIdx.x;
    if (idx >= 512 * K) return;
    int n = idx / K, k = idx - n * K;
    const int cg = n >> 7;
    const int gate = (n >> 5) & 3;
    const int j = cg * 32 + (n & 31);
    const float* W = a.W[lyr];
    const float* U = a.U[lyr];
    float v;
    if (gate == 0)      v = (k < Kx) ? W[(size_t)k * 384 + j] : U[(size_t)(k - Kx) * 384 + j];
    else if (gate == 1) v = (k < Kx) ? W[(size_t)k * 384 + 128 + j] : U[(size_t)(k - Kx) * 384 + 128 + j];
    else if (gate == 2) v = (k < Kx) ? W[(size_t)k * 384 + 256 + j] : 0.f;
    else                v = (k >= Kx) ? U[(size_t)(k - Kx) * 384 + 256 + j] : 0.f;
    size_t o = a.off[lyr] + (size_t)n * K + (size_t)(k & ~127) + kswz128(k & 127, n);
    bt16[o] = __builtin_bit_cast(ushort_t, __float2half(v));
}

// ---------------- edge message GEMM: single-shot K=128, fp16 MFMA ----------------
__global__ __launch_bounds__(256) void edge_mfma(
    const ushort_t* __restrict__ hP,
    const int*   __restrict__ eids,
    const int*   __restrict__ perm,
    const int*   __restrict__ rank,
    const int*   __restrict__ meta,
    const ushort_t* __restrict__ wt16, // (T,128,128) [t][n][kswz128]
    const float* __restrict__ bias,    // (T,H)
    ushort_t*    __restrict__ msg16)   // (E,H) fp16, target-sorted
{
    __shared__ ushort_t Ah[EPB * 128];   // 16KB
    __shared__ ushort_t Bh[128 * 128];   // 32KB
    __shared__ int srcnode[EPB], outrow[EPB];
    const int tid = threadIdx.x;
    const int b = blockIdx.x;
    const int nb = meta[27 + T_];
    if (b >= nb) return;
    int t = 0;
    while (b >= meta[27 + t + 1]) t++;
    const int chunk = b - meta[27 + t];
    const int c0 = meta[t] - chunk * EPB;
    const int base = meta[9 + t] + chunk * EPB;
    const int cnt = (c0 > EPB) ? EPB : c0;

    if (tid < EPB) {
        int e = perm[base + ((tid < cnt) ? tid : 0)];
        srcnode[tid] = eids[e * 4 + 1] * N_ + eids[e * 4 + 2];
        outrow[tid]  = rank[e];
    }
    __syncthreads();

    const int w = tid >> 6, l = tid & 63;
    const int wr = (w >> 1) * 32, wc = (w & 1) * 64;
    const int l16 = l & 15, g = l >> 4;
    const int lr = l >> 4, s = l & 15;

    {
        const ushort_t* wrow = wt16 + (size_t)t * (128 * 128);
#pragma unroll
        for (int q = 0; q < 8; ++q) {
            const int n = w * 32 + q * 4 + lr;
            __builtin_amdgcn_global_load_lds(
                (const __attribute__((address_space(1))) void*)(wrow + (size_t)n * 128 + s * 8),
                (__attribute__((address_space(3))) void*)&Bh[(w * 32 + q * 4) * 128], 16, 0, 0);
        }
#pragma unroll
        for (int q = 0; q < 4; ++q) {
            const int row = w * 16 + q * 4 + lr;
            const int node = srcnode[row];
            __builtin_amdgcn_global_load_lds(
                (const __attribute__((address_space(1))) void*)(hP + (size_t)node * H_ + aslot_src(s, row)),
                (__attribute__((address_space(3))) void*)&Ah[(w * 16 + q * 4) * 128], 16, 0, 0);
        }
    }
    __syncthreads();

    f32x4 acc[2][4];
#pragma unroll
    for (int i = 0; i < 2; ++i)
#pragma unroll
        for (int j = 0; j < 4; ++j) acc[i][j] = (f32x4){0.f, 0.f, 0.f, 0.f};

    __builtin_amdgcn_s_setprio(1);
#pragma unroll
    for (int kc = 0; kc < 4; ++kc) {
        f16x8 fah[2], fbh[4];
#pragma unroll
        for (int f = 0; f < 2; ++f)
            fah[f] = *reinterpret_cast<const f16x8*>(&Ah[ldoff(wr + f * 16 + l16, kc, g)]);
#pragma unroll
        for (int f = 0; f < 4; ++f)
            fbh[f] = *reinterpret_cast<const f16x8*>(&Bh[ldoff(wc + f * 16 + l16, kc, g)]);
#pragma unroll
        for (int mf = 0; mf < 2; ++mf)
#pragma unroll
            for (int nf = 0; nf < 4; ++nf)
                acc[mf][nf] = __builtin_amdgcn_mfma_f32_16x16x32_f16(fah[mf], fbh[nf], acc[mf][nf], 0, 0, 0);
    }
    __builtin_amdgcn_s_setprio(0);

#pragma unroll
    for (int mf = 0; mf < 2; ++mf) {
        const int rbase = wr + mf * 16 + g * 4;
#pragma unroll
        for (int nf = 0; nf < 4; ++nf) {
            const int col = wc + nf * 16 + l16;
            const float bv = bias[t * H_ + col];
#pragma unroll
            for (int r = 0; r < 4; ++r) {
                const int row = rbase + r;
                if (row < cnt)
                    msg16[(size_t)outrow[row] * H_ + col] =
                        __builtin_bit_cast(ushort_t, __float2half(acc[mf][nf][r] + bv));
            }
        }
    }
}

// ---------------- fused gates GEMM + GRU nonlinearity + inline aggregation ----------------
// Block (bx, cg): rows m0..m0+63, gate cols cg*32..cg*32+31 of ALL 4 gates.
// For chunk == aggChunk, A is built inline: segmented fp32 sum over msg16
// (target-sorted, tstart ranges) -> fp16 -> ds_write to the same phys slot
// the gload path fills. Other chunks: global_load_lds from fp16 planes.
__global__ __launch_bounds__(256) void gru_mfma(
    const ushort_t* __restrict__ s0P, const ushort_t* __restrict__ s1P,
    const ushort_t* __restrict__ s2P, const ushort_t* __restrict__ s3P,
    const ushort_t* __restrict__ msg16, const int* __restrict__ tstart,
    const int aggChunk,
    const ushort_t* __restrict__ bt16,
    const int K,
    const float* __restrict__ hcur, const float* __restrict__ b,  // (2,384) flat
    float* __restrict__ hout, ushort_t* __restrict__ outP)
{
    __shared__ ushort_t Ah[64 * 128];    // 16KB
    __shared__ ushort_t Bh[128 * 128];   // 32KB
    const ushort_t* sP[4] = {s0P, s1P, s2P, s3P};
    const int tid = threadIdx.x;
    const int m0 = blockIdx.x * 64;
    const int cg = blockIdx.y;
    const int w = tid >> 6, l = tid & 63;
    const int l16 = l & 15, lg = l >> 4;
    const int lr = l >> 4, s = l & 15;

    f32x4 acc[8];
#pragma unroll
    for (int i = 0; i < 8; ++i) acc[i] = (f32x4){0.f, 0.f, 0.f, 0.f};

    for (int c = 0; c < K; c += 128) {
        const int ch = c >> 7;
        if (c) __syncthreads();          // protect LDS before overwrite
        // stage B first: wave w rows w*32..+31 (8 instrs; swizzle baked)
#pragma unroll
        for (int q = 0; q < 8; ++q) {
            const int n = w * 32 + q * 4 + lr;
            __builtin_amdgcn_global_load_lds(
                (const __attribute__((address_space(1))) void*)(bt16 + (size_t)(cg * 128 + n) * K + c + s * 8),
                (__attribute__((address_space(3))) void*)&Bh[(w * 32 + q * 4) * 128], 16, 0, 0);
        }
        if (ch == aggChunk) {
            // inline aggregation: lane covers (row, slot); 8 logical k's per slot
#pragma unroll
            for (int q = 0; q < 4; ++q) {
                const int row = w * 16 + q * 4 + lr;
                const int koff = aslot_src(s, row);
                const int gn = m0 + row;
                const int sBeg = tstart[gn], sEnd = tstart[gn + 1];
                float a0 = 0.f, a1 = 0.f, a2 = 0.f, a3 = 0.f;
                float a4 = 0.f, a5 = 0.f, a6 = 0.f, a7 = 0.f;
                for (int i = sBeg; i < sEnd; ++i) {
                    const ushort_t* mp = msg16 + (size_t)i * H_ + koff;
                    ushort4 u0 = *reinterpret_cast<const ushort4*>(mp);
                    ushort4 u1 = *reinterpret_cast<const ushort4*>(mp + 4);
                    a0 += __half2float(__builtin_bit_cast(__half, u0.x));
                    a1 += __half2float(__builtin_bit_cast(__half, u0.y));
                    a2 += __half2float(__builtin_bit_cast(__half, u0.z));
                    a3 += __half2float(__builtin_bit_cast(__half, u0.w));
                    a4 += __half2float(__builtin_bit_cast(__half, u1.x));
                    a5 += __half2float(__builtin_bit_cast(__half, u1.y));
                    a6 += __half2float(__builtin_bit_cast(__half, u1.z));
                    a7 += __half2float(__builtin_bit_cast(__half, u1.w));
                }
                __align__(16) ushort_t hv[8];
                hv[0] = __builtin_bit_cast(ushort_t, __float2half(a0));
                hv[1] = __builtin_bit_cast(ushort_t, __float2half(a1));
                hv[2] = __builtin_bit_cast(ushort_t, __float2half(a2));
                hv[3] = __builtin_bit_cast(ushort_t, __float2half(a3));
                hv[4] = __builtin_bit_cast(ushort_t, __float2half(a4));
                hv[5] = __builtin_bit_cast(ushort_t, __float2half(a5));
                hv[6] = __builtin_bit_cast(ushort_t, __float2half(a6));
                hv[7] = __builtin_bit_cast(ushort_t, __float2half(a7));
                *reinterpret_cast<ushort8*>(&Ah[row * 128 + s * 8]) =
                    *reinterpret_cast<ushort8*>(hv);
            }
        } else {
            const ushort_t* sp = sP[ch];
#pragma unroll
            for (int q = 0; q < 4; ++q) {
                const int row = w * 16 + q * 4 + lr;
                __builtin_amdgcn_global_load_lds(
                    (const __attribute__((address_space(1))) void*)(sp + (size_t)(m0 + row) * H_ + aslot_src(s, row)),
                    (__attribute__((address_space(3))) void*)&Ah[(w * 16 + q * 4) * 128], 16, 0, 0);
            }
        }
        __syncthreads();
        __builtin_amdgcn_s_setprio(1);
#pragma unroll
        for (int kc = 0; kc < 4; ++kc) {
            f16x8 fah = *reinterpret_cast<const f16x8*>(&Ah[ldoff(w * 16 + l16, kc, lg)]);
            f16x8 fbh[8];
#pragma unroll
            for (int nf = 0; nf < 8; ++nf)
                fbh[nf] = *reinterpret_cast<const f16x8*>(&Bh[ldoff(nf * 16 + l16, kc, lg)]);
#pragma unroll
            for (int nf = 0; nf < 8; ++nf)
                acc[nf] = __builtin_amdgcn_mfma_f32_16x16x32_f16(fah, fbh[nf], acc[nf], 0, 0, 0);
        }
        __builtin_amdgcn_s_setprio(0);
    }

    // epilogue: lane holds z,r,xh,hh at nf = gate*2 + cpart, col c = cpart*16+l16.
    // C/D layout: col(n'') = nf*16 + l16, row = w*16 + lg*4 + reg.
#pragma unroll
    for (int cpart = 0; cpart < 2; ++cpart) {
        const int j = cg * 32 + cpart * 16 + l16;
        const float bz  = b[j] + b[384 + j];
        const float br  = b[128 + j] + b[512 + j];
        const float bxh = b[256 + j];
        const float bhh = b[640 + j];
#pragma unroll
        for (int r = 0; r < 4; ++r) {
            const int m = m0 + w * 16 + lg * 4 + r;
            const float zp = acc[cpart][r] + bz;
            const float rp = acc[2 + cpart][r] + br;
            const float xh = acc[4 + cpart][r] + bxh;
            const float hh = acc[6 + cpart][r] + bhh;
            const float z  = 1.f / (1.f + expf(-zp));
            const float rr = 1.f / (1.f + expf(-rp));
            const float cand = tanhf(xh + rr * hh);
            const float hv = hcur[(size_t)m * H_ + j];
            const float o = z * hv + (1.f - z) * cand;
            hout[(size_t)m * H_ + j] = o;
            outP[(size_t)m * H_ + j] = __builtin_bit_cast(ushort_t, __float2half(o));
        }
    }
}

// ---------------- host orchestration ----------------
extern "C" void kernel_launch(void* const* d_in, const int* in_sizes, int n_in,
                              void* d_out, int out_size, void* d_ws, size_t ws_size,
                              hipStream_t stream) {
    const float* states = (const float*)d_in[0];
    const int*   eids   = (const int*)  d_in[1];
    const float* tw     = (const float*)d_in[2];   // (4,T,H,H)
    const float* tb     = (const float*)d_in[3];   // (4,T,H)
    const float* gW[4]  = { (const float*)d_in[4],  (const float*)d_in[7],
                            (const float*)d_in[10], (const float*)d_in[13] };
    const float* gU[4]  = { (const float*)d_in[5],  (const float*)d_in[8],
                            (const float*)d_in[11], (const float*)d_in[14] };
    const float* gb[4]  = { (const float*)d_in[6],  (const float*)d_in[9],
                            (const float*)d_in[12], (const float*)d_in[15] };
    float* out = (float*)d_out;

    const int KL[4]   = {256, 384, 256, 512};              // IN_DIM + 128 per layer
    const int AGGC[4] = {0, 1, 0, 2};                      // agg chunk index per layer
    const size_t KOFF[4] = {0, 512ull*256, 512ull*(256+384), 512ull*(256+384+256)};
    const size_t BT_TOT  = 512ull * (256 + 384 + 256 + 512);   // 720896 ushorts
    const size_t WT_L    = (size_t)T_ * H_ * H_;               // per-layer W plane
    const size_t PL      = (size_t)BN_ * H_;                   // plane elems

    char* ws = (char*)d_ws;
    float* bufA = (float*)ws; ws += PL * 4;
    float* bufB = (float*)ws; ws += PL * 4;
    float* bufC = (float*)ws; ws += PL * 4;
    char*  msgR = ws;         ws += (size_t)E_ * H_ * 2;    // 33.5MB: msg16
    ushort_t* stP = (ushort_t*)ws; ws += PL * 2;
    ushort_t* paP = (ushort_t*)ws; ws += PL * 2;
    ushort_t* pbP = (ushort_t*)ws; ws += PL * 2;
    ushort_t* pcP = (ushort_t*)ws; ws += PL * 2;
    ushort_t* btAll = (ushort_t*)ws; ws += BT_TOT * 2;
    ushort_t* wtAll = (ushort_t*)ws; ws += 4 * WT_L * 2;
    int*   perm  = (int*)ws;  ws += (size_t)E_ * 4;
    int*   rank  = (int*)ws;  ws += (size_t)E_ * 4;
    int*   tcnt  = (int*)ws;  ws += (size_t)BN_ * 4;
    int*   toff  = (int*)ws;  ws += (size_t)BN_ * 4;
    int*   tstart= (int*)ws;  ws += (size_t)(BN_ + 1) * 4;
    int*   meta  = (int*)ws;  ws += 64 * 4;
    ushort_t* msg16 = (ushort_t*)msgR;

    // ---- one-time sorts + casts (batched) ----
    hipMemsetAsync(meta, 0, 40 * sizeof(int), stream);
    hipMemsetAsync(tcnt, 0, BN_ * sizeof(int), stream);
    count_all<<<(E_ + 255) / 256, 256, 0, stream>>>(eids, meta, tcnt);
    scan_all  <<<1, 256, 0, stream>>>(tcnt, tstart, toff, meta);
    scatter_all<<<(E_ + 255) / 256, 256, 0, stream>>>(eids, meta, toff, perm, rank);
    cast_state<<<(int)(PL / 4 / 256), 256, 0, stream>>>(states, stP);

    BtArgs bta;
    for (int lyr = 0; lyr < 4; ++lyr) {
        bta.W[lyr] = gW[lyr]; bta.U[lyr] = gU[lyr];
        bta.off[lyr] = KOFF[lyr]; bta.K[lyr] = KL[lyr];
    }
    build_bt2<<<dim3((512 * 512 + 255) / 256, 4), 256, 0, stream>>>(bta, btAll);
    build_wt<<<(4 * (int)WT_L + 255) / 256, 256, 0, stream>>>(tw, wtAll);

    // step schedule: layers [0,0,0, 1, 2,2,2, 3]
    const int layer_of[8] = {0, 0, 0, 1, 2, 2, 2, 3};
    float*    target[8]  = {bufA, bufB, bufC, bufA, bufB, bufA, bufB, out};
    ushort_t* targetP[8] = {paP, pbP, pcP, paP, pbP, paP, pbP, paP};

    const float* cur = states;
    const ushort_t* curP = stP;
    const int edge_grid = E_ / EPB + T_;

    for (int s = 0; s < 8; ++s) {
        const int l = layer_of[s];
        edge_mfma<<<edge_grid, 256, 0, stream>>>(
            curP, eids, perm, rank, meta,
            wtAll + l * WT_L, tb + (size_t)l * T_ * H_, msg16);

        // fp16 A sources in order [res..., agg(inline), cur]
        const ushort_t *p0, *p1, *p2, *p3;
        if (l == 0 || l == 2)      { p0 = nullptr; p1 = curP; p2 = nullptr; p3 = nullptr; }
        else if (l == 1)           { p0 = stP; p1 = nullptr;  p2 = curP;    p3 = nullptr; }
        else                       { p0 = stP; p1 = pcP;  p2 = nullptr;     p3 = curP;    }

        float* nxt = target[s];
        dim3 ggrid(BN_ / 64, 4);
        gru_mfma<<<ggrid, 256, 0, stream>>>(p0, p1, p2, p3,
                                            msg16, tstart, AGGC[l],
                                            btAll + KOFF[l], KL[l],
                                            cur, gb[l], nxt, targetP[s]);
        cur = nxt; curP = targetP[s];
    }
}

// Round 21
// 469.909 us; speedup vs baseline: 1.4599x; 1.4599x over previous
//
#include <hip/hip_runtime.h>
#include <hip/hip_fp16.h>
#include <math.h>

#define B_  32
#define N_  512
#define H_  128
#define E_  131072
#define T_  9
#define BN_ (B_*N_)
#define EPB 64   // edges per block in edge MFMA GEMM

typedef unsigned short ushort_t;
typedef __attribute__((ext_vector_type(8))) _Float16 f16x8;
typedef __attribute__((ext_vector_type(8))) unsigned short ushort8;
typedef __attribute__((ext_vector_type(4))) float f32x4;

// 128-k-row swizzle for B LDS tiles: XOR 32-chunk bits and 16B-slot bits with
// row bits -> low-way LDS bank access for ds_read_b128 at 256B row stride.
__device__ __forceinline__ int kswz128(int k, int n) {
    int kc = ((k >> 5) ^ (n >> 3)) & 3;
    int sp = ((k >> 3) ^ (n >> 1)) & 3;
    return (kc << 5) | (sp << 3) | (k & 7);
}
// logical k-offset feeding phys 16B slot s of (local) row (A-plane source swizzle)
__device__ __forceinline__ int aslot_src(int s, int row) {
    int kc = ((s >> 2) ^ (row >> 3)) & 3;
    int kg = ((s & 3) ^ (row >> 1)) & 3;
    return (kc << 5) + (kg << 3);
}
// LDS ushort offset for (local row, logical 32-chunk kc, 8-elem group g)
__device__ __forceinline__ int ldoff(int row, int kc, int g) {
    return row * 128 + (((kc ^ (row >> 3)) & 3) << 5) + (((g ^ (row >> 1)) & 3) << 3);
}

// meta layout (ints): [0..8]=cnt, [9..17]=start, [18..26]=off(atomic), [27..36]=cumBlocks(10)

// ---------------- fused histograms (type + target) ----------------
__global__ void count_all(const int* __restrict__ eids, int* __restrict__ meta,
                          int* __restrict__ tcnt) {
    __shared__ int lc[T_];
    if (threadIdx.x < T_) lc[threadIdx.x] = 0;
    __syncthreads();
    int e = blockIdx.x * 256 + threadIdx.x;
    if (e < E_) {
        int4 v = reinterpret_cast<const int4*>(eids)[e];
        atomicAdd(&lc[v.x], 1);
        atomicAdd(&tcnt[v.y * N_ + v.w], 1);
    }
    __syncthreads();
    if (threadIdx.x < T_ && lc[threadIdx.x]) atomicAdd(&meta[threadIdx.x], lc[threadIdx.x]);
}

// target scan + tiny type scan
__global__ void scan_all(const int* __restrict__ tcnt, int* __restrict__ tstart,
                         int* __restrict__ toff, int* __restrict__ meta) {
    __shared__ int bs[256];
    const int tid = threadIdx.x;
    if (tid == 0) {
        int s = 0;
        for (int t = 0; t < T_; ++t) { meta[9 + t] = s; meta[18 + t] = s; s += meta[t]; }
        int cb = 0;
        for (int t = 0; t < T_; ++t) { meta[27 + t] = cb; cb += (meta[t] + EPB - 1) / EPB; }
        meta[27 + T_] = cb;
    }
    const int chunk = BN_ / 256;   // 64
    const int base = tid * chunk;
    int s = 0;
    for (int i = 0; i < chunk; ++i) s += tcnt[base + i];
    bs[tid] = s;
    __syncthreads();
    if (tid == 0) { int acc = 0; for (int i = 0; i < 256; ++i) { int v = bs[i]; bs[i] = acc; acc += v; } }
    __syncthreads();
    int acc = bs[tid];
    for (int i = 0; i < chunk; ++i) {
        int v = tcnt[base + i];
        tstart[base + i] = acc; toff[base + i] = acc; acc += v;
    }
    if (tid == 255) tstart[BN_] = E_;
}

// ---------------- fused scatter (type perm + target rank) ----------------
__global__ void scatter_all(const int* __restrict__ eids, int* __restrict__ meta,
                            int* __restrict__ toff, int* __restrict__ perm,
                            int* __restrict__ rank) {
    __shared__ int lc[T_], lbase[T_];
    if (threadIdx.x < T_) lc[threadIdx.x] = 0;
    __syncthreads();
    int e = blockIdx.x * 256 + threadIdx.x;
    int4 v = {0, 0, 0, 0};
    int lp = 0;
    if (e < E_) { v = reinterpret_cast<const int4*>(eids)[e]; lp = atomicAdd(&lc[v.x], 1); }
    __syncthreads();
    if (threadIdx.x < T_ && lc[threadIdx.x])
        lbase[threadIdx.x] = atomicAdd(&meta[18 + threadIdx.x], lc[threadIdx.x]);
    __syncthreads();
    if (e < E_) {
        perm[lbase[v.x] + lp] = e;
        rank[e] = atomicAdd(&toff[v.y * N_ + v.w], 1);
    }
}

// ---------------- state cast: fp32 (BN,H) -> fp16 plane ----------------
__global__ __launch_bounds__(256) void cast_state(const float* __restrict__ in,
                                                  ushort_t* __restrict__ hP) {
    int i = blockIdx.x * 256 + threadIdx.x;      // over BN*H/4
    float4 v = reinterpret_cast<const float4*>(in)[i];
    ushort4 h;
    h.x = __builtin_bit_cast(ushort_t, __float2half(v.x));
    h.y = __builtin_bit_cast(ushort_t, __float2half(v.y));
    h.z = __builtin_bit_cast(ushort_t, __float2half(v.z));
    h.w = __builtin_bit_cast(ushort_t, __float2half(v.w));
    reinterpret_cast<ushort4*>(hP)[i] = h;
}

// ---------------- weight fp16 transpose for edge MFMA (all layers) ----------------
// in: (4,T,H,H) = W[l][t][k][n]; out: (4,T,128,128) = [lt][n][kswz128(k,n)] fp16
__global__ void build_wt(const float* __restrict__ W, ushort_t* __restrict__ wt16) {
    int idx = blockIdx.x * 256 + threadIdx.x;
    if (idx >= 4 * T_ * H_ * H_) return;
    int lt = idx / (H_ * H_);
    int rem = idx - lt * H_ * H_;
    int n = rem >> 7, k = rem & 127;
    float v = W[(size_t)lt * H_ * H_ + k * H_ + n];
    size_t o = (size_t)lt * H_ * H_ + n * 128 + kswz128(k, n);
    wt16[o] = __builtin_bit_cast(ushort_t, __float2half(v));
}

// ---------------- B2 build: gate-interleaved padded GRU weights ----------------
// Row n' = cg*128 + gate*32 + c covers gate column j = cg*32 + c; every gate
// zero-padded to span [0,K). gate: 0=z 1=r 2=xh 3=hh.
struct BtArgs {
    const float* W[4];
    const float* U[4];
    unsigned long long off[4];
    int K[4];
};
__global__ void build_bt2(BtArgs a, ushort_t* __restrict__ bt16) {
    const int lyr = blockIdx.y;
    const int K = a.K[lyr];
    const int Kx = K - 128;
    int idx = blockIdx.x * 256 + threadIdx.x;
    if (idx >= 512 * K) return;
    int n = idx / K, k = idx - n * K;
    const int cg = n >> 7;
    const int gate = (n >> 5) & 3;
    const int j = cg * 32 + (n & 31);
    const float* W = a.W[lyr];
    const float* U = a.U[lyr];
    float v;
    if (gate == 0)      v = (k < Kx) ? W[(size_t)k * 384 + j] : U[(size_t)(k - Kx) * 384 + j];
    else if (gate == 1) v = (k < Kx) ? W[(size_t)k * 384 + 128 + j] : U[(size_t)(k - Kx) * 384 + 128 + j];
    else if (gate == 2) v = (k < Kx) ? W[(size_t)k * 384 + 256 + j] : 0.f;
    else                v = (k >= Kx) ? U[(size_t)(k - Kx) * 384 + 256 + j] : 0.f;
    size_t o = a.off[lyr] + (size_t)n * K + (size_t)(k & ~127) + kswz128(k & 127, n);
    bt16[o] = __builtin_bit_cast(ushort_t, __float2half(v));
}

// ---------------- edge message GEMM: single-shot K=128, fp16 MFMA ----------------
__global__ __launch_bounds__(256) void edge_mfma(
    const ushort_t* __restrict__ hP,
    const int*   __restrict__ eids,
    const int*   __restrict__ perm,
    const int*   __restrict__ rank,
    const int*   __restrict__ meta,
    const ushort_t* __restrict__ wt16, // (T,128,128) [t][n][kswz128]
    const float* __restrict__ bias,    // (T,H)
    ushort_t*    __restrict__ msg16)   // (E,H) fp16, target-sorted
{
    __shared__ ushort_t Ah[EPB * 128];   // 16KB
    __shared__ ushort_t Bh[128 * 128];   // 32KB
    __shared__ int srcnode[EPB], outrow[EPB];
    const int tid = threadIdx.x;
    const int b = blockIdx.x;
    const int nb = meta[27 + T_];
    if (b >= nb) return;
    int t = 0;
    while (b >= meta[27 + t + 1]) t++;
    const int chunk = b - meta[27 + t];
    const int c0 = meta[t] - chunk * EPB;
    const int base = meta[9 + t] + chunk * EPB;
    const int cnt = (c0 > EPB) ? EPB : c0;

    if (tid < EPB) {
        int e = perm[base + ((tid < cnt) ? tid : 0)];
        srcnode[tid] = eids[e * 4 + 1] * N_ + eids[e * 4 + 2];
        outrow[tid]  = rank[e];
    }
    __syncthreads();

    const int w = tid >> 6, l = tid & 63;
    const int wr = (w >> 1) * 32, wc = (w & 1) * 64;
    const int l16 = l & 15, g = l >> 4;
    const int lr = l >> 4, s = l & 15;

    {
        const ushort_t* wrow = wt16 + (size_t)t * (128 * 128);
#pragma unroll
        for (int q = 0; q < 8; ++q) {
            const int n = w * 32 + q * 4 + lr;
            __builtin_amdgcn_global_load_lds(
                (const __attribute__((address_space(1))) void*)(wrow + (size_t)n * 128 + s * 8),
                (__attribute__((address_space(3))) void*)&Bh[(w * 32 + q * 4) * 128], 16, 0, 0);
        }
#pragma unroll
        for (int q = 0; q < 4; ++q) {
            const int row = w * 16 + q * 4 + lr;
            const int node = srcnode[row];
            __builtin_amdgcn_global_load_lds(
                (const __attribute__((address_space(1))) void*)(hP + (size_t)node * H_ + aslot_src(s, row)),
                (__attribute__((address_space(3))) void*)&Ah[(w * 16 + q * 4) * 128], 16, 0, 0);
        }
    }
    __syncthreads();

    f32x4 acc[2][4];
#pragma unroll
    for (int i = 0; i < 2; ++i)
#pragma unroll
        for (int j = 0; j < 4; ++j) acc[i][j] = (f32x4){0.f, 0.f, 0.f, 0.f};

#pragma unroll
    for (int kc = 0; kc < 4; ++kc) {
        f16x8 fah[2], fbh[4];
#pragma unroll
        for (int f = 0; f < 2; ++f)
            fah[f] = *reinterpret_cast<const f16x8*>(&Ah[ldoff(wr + f * 16 + l16, kc, g)]);
#pragma unroll
        for (int f = 0; f < 4; ++f)
            fbh[f] = *reinterpret_cast<const f16x8*>(&Bh[ldoff(wc + f * 16 + l16, kc, g)]);
#pragma unroll
        for (int mf = 0; mf < 2; ++mf)
#pragma unroll
            for (int nf = 0; nf < 4; ++nf)
                acc[mf][nf] = __builtin_amdgcn_mfma_f32_16x16x32_f16(fah[mf], fbh[nf], acc[mf][nf], 0, 0, 0);
    }

#pragma unroll
    for (int mf = 0; mf < 2; ++mf) {
        const int rbase = wr + mf * 16 + g * 4;
#pragma unroll
        for (int nf = 0; nf < 4; ++nf) {
            const int col = wc + nf * 16 + l16;
            const float bv = bias[t * H_ + col];
#pragma unroll
            for (int r = 0; r < 4; ++r) {
                const int row = rbase + r;
                if (row < cnt)
                    msg16[(size_t)outrow[row] * H_ + col] =
                        __builtin_bit_cast(ushort_t, __float2half(acc[mf][nf][r] + bv));
            }
        }
    }
}

// ---------------- segmented aggregation (fp16 in; fp16 plane out) ----------------
// 16 nodes/block; 16 lanes/node, 8 cols each (16B ushort8 loads, fully coalesced)
__global__ __launch_bounds__(256) void aggregate(
    const ushort_t* __restrict__ msg16,
    const int*      __restrict__ tstart,
    ushort_t*       __restrict__ agP)
{
    const int n  = blockIdx.x * 16 + (threadIdx.x >> 4);
    const int jc = (threadIdx.x & 15) * 8;
    const int s = tstart[n], e_end = tstart[n + 1];
    float a0 = 0.f, a1 = 0.f, a2 = 0.f, a3 = 0.f;
    float a4 = 0.f, a5 = 0.f, a6 = 0.f, a7 = 0.f;
    for (int i = s; i < e_end; ++i) {
        ushort8 u = *reinterpret_cast<const ushort8*>(&msg16[(size_t)i * H_ + jc]);
        a0 += __half2float(__builtin_bit_cast(__half, (ushort_t)u[0]));
        a1 += __half2float(__builtin_bit_cast(__half, (ushort_t)u[1]));
        a2 += __half2float(__builtin_bit_cast(__half, (ushort_t)u[2]));
        a3 += __half2float(__builtin_bit_cast(__half, (ushort_t)u[3]));
        a4 += __half2float(__builtin_bit_cast(__half, (ushort_t)u[4]));
        a5 += __half2float(__builtin_bit_cast(__half, (ushort_t)u[5]));
        a6 += __half2float(__builtin_bit_cast(__half, (ushort_t)u[6]));
        a7 += __half2float(__builtin_bit_cast(__half, (ushort_t)u[7]));
    }
    ushort8 h;
    h[0] = __builtin_bit_cast(ushort_t, __float2half(a0));
    h[1] = __builtin_bit_cast(ushort_t, __float2half(a1));
    h[2] = __builtin_bit_cast(ushort_t, __float2half(a2));
    h[3] = __builtin_bit_cast(ushort_t, __float2half(a3));
    h[4] = __builtin_bit_cast(ushort_t, __float2half(a4));
    h[5] = __builtin_bit_cast(ushort_t, __float2half(a5));
    h[6] = __builtin_bit_cast(ushort_t, __float2half(a6));
    h[7] = __builtin_bit_cast(ushort_t, __float2half(a7));
    *reinterpret_cast<ushort8*>(&agP[(size_t)n * H_ + jc]) = h;
}

// ---------------- fused gates GEMM + GRU nonlinearity ----------------
// Block (bx, cg): rows m0..m0+63, gate cols cg*32..cg*32+31 of ALL 4 gates.
// B tile rows n'' = gate*32 + c (128 rows x K, zero-padded per gate).
// Wave w = 16 M-rows x all 128 n''; lane holds z,r,xh,hh for its (row,col) pairs.
__global__ __launch_bounds__(256) void gru_mfma(
    const ushort_t* __restrict__ s0P, const ushort_t* __restrict__ s1P,
    const ushort_t* __restrict__ s2P, const ushort_t* __restrict__ s3P,
    const ushort_t* __restrict__ bt16,
    const int K,
    const float* __restrict__ hcur, const float* __restrict__ b,  // (2,384) flat
    float* __restrict__ hout, ushort_t* __restrict__ outP)
{
    __shared__ ushort_t Ah[64 * 128];    // 16KB
    __shared__ ushort_t Bh[128 * 128];   // 32KB
    const ushort_t* sP[4] = {s0P, s1P, s2P, s3P};
    const int tid = threadIdx.x;
    const int m0 = blockIdx.x * 64;
    const int cg = blockIdx.y;
    const int w = tid >> 6, l = tid & 63;
    const int l16 = l & 15, lg = l >> 4;
    const int lr = l >> 4, s = l & 15;

    f32x4 acc[8];
#pragma unroll
    for (int i = 0; i < 8; ++i) acc[i] = (f32x4){0.f, 0.f, 0.f, 0.f};

    for (int c = 0; c < K; c += 128) {
        if (c) __syncthreads();          // protect LDS before overwrite
        const ushort_t* sp = sP[c >> 7];
        // stage A: wave w rows w*16..+15 (4 instrs; per-lane pre-swizzled source)
#pragma unroll
        for (int q = 0; q < 4; ++q) {
            const int row = w * 16 + q * 4 + lr;
            __builtin_amdgcn_global_load_lds(
                (const __attribute__((address_space(1))) void*)(sp + (size_t)(m0 + row) * H_ + aslot_src(s, row)),
                (__attribute__((address_space(3))) void*)&Ah[(w * 16 + q * 4) * 128], 16, 0, 0);
        }
        // stage B: wave w rows w*32..+31 (8 instrs; swizzle baked in global layout)
#pragma unroll
        for (int q = 0; q < 8; ++q) {
            const int n = w * 32 + q * 4 + lr;
            __builtin_amdgcn_global_load_lds(
                (const __attribute__((address_space(1))) void*)(bt16 + (size_t)(cg * 128 + n) * K + c + s * 8),
                (__attribute__((address_space(3))) void*)&Bh[(w * 32 + q * 4) * 128], 16, 0, 0);
        }
        __syncthreads();
#pragma unroll
        for (int kc = 0; kc < 4; ++kc) {
            f16x8 fah = *reinterpret_cast<const f16x8*>(&Ah[ldoff(w * 16 + l16, kc, lg)]);
            f16x8 fbh[8];
#pragma unroll
            for (int nf = 0; nf < 8; ++nf)
                fbh[nf] = *reinterpret_cast<const f16x8*>(&Bh[ldoff(nf * 16 + l16, kc, lg)]);
#pragma unroll
            for (int nf = 0; nf < 8; ++nf)
                acc[nf] = __builtin_amdgcn_mfma_f32_16x16x32_f16(fah, fbh[nf], acc[nf], 0, 0, 0);
        }
    }

    // epilogue: lane holds z,r,xh,hh at nf = gate*2 + cpart, col c = cpart*16+l16.
    // C/D layout: col(n'') = nf*16 + l16, row = w*16 + lg*4 + reg.
#pragma unroll
    for (int cpart = 0; cpart < 2; ++cpart) {
        const int j = cg * 32 + cpart * 16 + l16;
        const float bz  = b[j] + b[384 + j];
        const float br  = b[128 + j] + b[512 + j];
        const float bxh = b[256 + j];
        const float bhh = b[640 + j];
#pragma unroll
        for (int r = 0; r < 4; ++r) {
            const int m = m0 + w * 16 + lg * 4 + r;
            const float zp = acc[cpart][r] + bz;
            const float rp = acc[2 + cpart][r] + br;
            const float xh = acc[4 + cpart][r] + bxh;
            const float hh = acc[6 + cpart][r] + bhh;
            const float z  = 1.f / (1.f + expf(-zp));
            const float rr = 1.f / (1.f + expf(-rp));
            const float cand = tanhf(xh + rr * hh);
            const float hv = hcur[(size_t)m * H_ + j];
            const float o = z * hv + (1.f - z) * cand;
            hout[(size_t)m * H_ + j] = o;
            outP[(size_t)m * H_ + j] = __builtin_bit_cast(ushort_t, __float2half(o));
        }
    }
}

// ---------------- host orchestration ----------------
extern "C" void kernel_launch(void* const* d_in, const int* in_sizes, int n_in,
                              void* d_out, int out_size, void* d_ws, size_t ws_size,
                              hipStream_t stream) {
    const float* states = (const float*)d_in[0];
    const int*   eids   = (const int*)  d_in[1];
    const float* tw     = (const float*)d_in[2];   // (4,T,H,H)
    const float* tb     = (const float*)d_in[3];   // (4,T,H)
    const float* gW[4]  = { (const float*)d_in[4],  (const float*)d_in[7],
                            (const float*)d_in[10], (const float*)d_in[13] };
    const float* gU[4]  = { (const float*)d_in[5],  (const float*)d_in[8],
                            (const float*)d_in[11], (const float*)d_in[14] };
    const float* gb[4]  = { (const float*)d_in[6],  (const float*)d_in[9],
                            (const float*)d_in[12], (const float*)d_in[15] };
    float* out = (float*)d_out;

    const int KL[4]   = {256, 384, 256, 512};              // IN_DIM + 128 per layer
    const size_t KOFF[4] = {0, 512ull*256, 512ull*(256+384), 512ull*(256+384+256)};
    const size_t BT_TOT  = 512ull * (256 + 384 + 256 + 512);   // 720896 ushorts
    const size_t WT_L    = (size_t)T_ * H_ * H_;               // per-layer W plane
    const size_t PL      = (size_t)BN_ * H_;                   // plane elems

    char* ws = (char*)d_ws;
    float* bufA = (float*)ws; ws += PL * 4;
    float* bufB = (float*)ws; ws += PL * 4;
    float* bufC = (float*)ws; ws += PL * 4;
    char*  msgR = ws;         ws += (size_t)E_ * H_ * 2;    // 33.5MB: msg16
    ushort_t* stP = (ushort_t*)ws; ws += PL * 2;
    ushort_t* paP = (ushort_t*)ws; ws += PL * 2;
    ushort_t* pbP = (ushort_t*)ws; ws += PL * 2;
    ushort_t* pcP = (ushort_t*)ws; ws += PL * 2;
    ushort_t* agP = (ushort_t*)ws; ws += PL * 2;
    ushort_t* btAll = (ushort_t*)ws; ws += BT_TOT * 2;
    ushort_t* wtAll = (ushort_t*)ws; ws += 4 * WT_L * 2;
    int*   perm  = (int*)ws;  ws += (size_t)E_ * 4;
    int*   rank  = (int*)ws;  ws += (size_t)E_ * 4;
    int*   tcnt  = (int*)ws;  ws += (size_t)BN_ * 4;
    int*   toff  = (int*)ws;  ws += (size_t)BN_ * 4;
    int*   tstart= (int*)ws;  ws += (size_t)(BN_ + 1) * 4;
    int*   meta  = (int*)ws;  ws += 64 * 4;
    ushort_t* msg16 = (ushort_t*)msgR;

    // ---- one-time sorts + casts (batched) ----
    hipMemsetAsync(meta, 0, 40 * sizeof(int), stream);
    hipMemsetAsync(tcnt, 0, BN_ * sizeof(int), stream);
    count_all<<<(E_ + 255) / 256, 256, 0, stream>>>(eids, meta, tcnt);
    scan_all  <<<1, 256, 0, stream>>>(tcnt, tstart, toff, meta);
    scatter_all<<<(E_ + 255) / 256, 256, 0, stream>>>(eids, meta, toff, perm, rank);
    cast_state<<<(int)(PL / 4 / 256), 256, 0, stream>>>(states, stP);

    BtArgs bta;
    for (int lyr = 0; lyr < 4; ++lyr) {
        bta.W[lyr] = gW[lyr]; bta.U[lyr] = gU[lyr];
        bta.off[lyr] = KOFF[lyr]; bta.K[lyr] = KL[lyr];
    }
    build_bt2<<<dim3((512 * 512 + 255) / 256, 4), 256, 0, stream>>>(bta, btAll);
    build_wt<<<(4 * (int)WT_L + 255) / 256, 256, 0, stream>>>(tw, wtAll);

    // step schedule: layers [0,0,0, 1, 2,2,2, 3]
    const int layer_of[8] = {0, 0, 0, 1, 2, 2, 2, 3};
    float*    target[8]  = {bufA, bufB, bufC, bufA, bufB, bufA, bufB, out};
    ushort_t* targetP[8] = {paP, pbP, pcP, paP, pbP, paP, pbP, paP};

    const float* cur = states;
    const ushort_t* curP = stP;
    const int edge_grid = E_ / EPB + T_;

    for (int s = 0; s < 8; ++s) {
        const int l = layer_of[s];
        edge_mfma<<<edge_grid, 256, 0, stream>>>(
            curP, eids, perm, rank, meta,
            wtAll + l * WT_L, tb + (size_t)l * T_ * H_, msg16);
        aggregate<<<BN_ / 16, 256, 0, stream>>>(msg16, tstart, agP);

        // A sources in order [res..., agg, cur]
        const ushort_t *p0, *p1, *p2, *p3;
        if (l == 0 || l == 2)      { p0 = agP; p1 = curP; p2 = nullptr; p3 = nullptr; }
        else if (l == 1)           { p0 = stP; p1 = agP;  p2 = curP;    p3 = nullptr; }
        else                       { p0 = stP; p1 = pcP;  p2 = agP;     p3 = curP;    }

        float* nxt = target[s];
        dim3 ggrid(BN_ / 64, 4);
        gru_mfma<<<ggrid, 256, 0, stream>>>(p0, p1, p2, p3,
                                            btAll + KOFF[l], KL[l],
                                            cur, gb[l], nxt, targetP[s]);
        cur = nxt; curP = targetP[s];
    }
}

// Round 22
// 456.142 us; speedup vs baseline: 1.5039x; 1.0302x over previous
//
#include <hip/hip_runtime.h>
#include <hip/hip_fp16.h>
#include <math.h>

#define B_  32
#define N_  512
#define H_  128
#define E_  131072
#define T_  9
#define BN_ (B_*N_)
#define EPB 64   // edges per block in edge MFMA GEMM

typedef unsigned short ushort_t;
typedef __attribute__((ext_vector_type(8))) _Float16 f16x8;
typedef __attribute__((ext_vector_type(8))) unsigned short ushort8;
typedef __attribute__((ext_vector_type(4))) float f32x4;

// 128-k-row swizzle for B LDS tiles: XOR 32-chunk bits and 16B-slot bits with
// row bits -> low-way LDS bank access for ds_read_b128 at 256B row stride.
__device__ __forceinline__ int kswz128(int k, int n) {
    int kc = ((k >> 5) ^ (n >> 3)) & 3;
    int sp = ((k >> 3) ^ (n >> 1)) & 3;
    return (kc << 5) | (sp << 3) | (k & 7);
}
// logical k-offset feeding phys 16B slot s of (local) row (A-plane source swizzle)
__device__ __forceinline__ int aslot_src(int s, int row) {
    int kc = ((s >> 2) ^ (row >> 3)) & 3;
    int kg = ((s & 3) ^ (row >> 1)) & 3;
    return (kc << 5) + (kg << 3);
}
// LDS ushort offset for (local row, logical 32-chunk kc, 8-elem group g)
__device__ __forceinline__ int ldoff(int row, int kc, int g) {
    return row * 128 + (((kc ^ (row >> 3)) & 3) << 5) + (((g ^ (row >> 1)) & 3) << 3);
}

// meta layout (ints): [0..8]=cnt, [9..17]=start, [18..26]=off(atomic), [27..36]=cumBlocks(10)

// ---------------- fused histograms (type + target) ----------------
__global__ void count_all(const int* __restrict__ eids, int* __restrict__ meta,
                          int* __restrict__ tcnt) {
    __shared__ int lc[T_];
    if (threadIdx.x < T_) lc[threadIdx.x] = 0;
    __syncthreads();
    int e = blockIdx.x * 256 + threadIdx.x;
    if (e < E_) {
        int4 v = reinterpret_cast<const int4*>(eids)[e];
        atomicAdd(&lc[v.x], 1);
        atomicAdd(&tcnt[v.y * N_ + v.w], 1);
    }
    __syncthreads();
    if (threadIdx.x < T_ && lc[threadIdx.x]) atomicAdd(&meta[threadIdx.x], lc[threadIdx.x]);
}

// target scan + tiny type scan
__global__ void scan_all(const int* __restrict__ tcnt, int* __restrict__ tstart,
                         int* __restrict__ toff, int* __restrict__ meta) {
    __shared__ int bs[256];
    const int tid = threadIdx.x;
    if (tid == 0) {
        int s = 0;
        for (int t = 0; t < T_; ++t) { meta[9 + t] = s; meta[18 + t] = s; s += meta[t]; }
        int cb = 0;
        for (int t = 0; t < T_; ++t) { meta[27 + t] = cb; cb += (meta[t] + EPB - 1) / EPB; }
        meta[27 + T_] = cb;
    }
    const int chunk = BN_ / 256;   // 64
    const int base = tid * chunk;
    int s = 0;
    for (int i = 0; i < chunk; ++i) s += tcnt[base + i];
    bs[tid] = s;
    __syncthreads();
    if (tid == 0) { int acc = 0; for (int i = 0; i < 256; ++i) { int v = bs[i]; bs[i] = acc; acc += v; } }
    __syncthreads();
    int acc = bs[tid];
    for (int i = 0; i < chunk; ++i) {
        int v = tcnt[base + i];
        tstart[base + i] = acc; toff[base + i] = acc; acc += v;
    }
    if (tid == 255) tstart[BN_] = E_;
}

// ---------------- fused scatter (type perm + target rank) ----------------
__global__ void scatter_all(const int* __restrict__ eids, int* __restrict__ meta,
                            int* __restrict__ toff, int* __restrict__ perm,
                            int* __restrict__ rank) {
    __shared__ int lc[T_], lbase[T_];
    if (threadIdx.x < T_) lc[threadIdx.x] = 0;
    __syncthreads();
    int e = blockIdx.x * 256 + threadIdx.x;
    int4 v = {0, 0, 0, 0};
    int lp = 0;
    if (e < E_) { v = reinterpret_cast<const int4*>(eids)[e]; lp = atomicAdd(&lc[v.x], 1); }
    __syncthreads();
    if (threadIdx.x < T_ && lc[threadIdx.x])
        lbase[threadIdx.x] = atomicAdd(&meta[18 + threadIdx.x], lc[threadIdx.x]);
    __syncthreads();
    if (e < E_) {
        perm[lbase[v.x] + lp] = e;
        rank[e] = atomicAdd(&toff[v.y * N_ + v.w], 1);
    }
}

// ---------------- state cast: fp32 (BN,H) -> fp16 plane ----------------
__global__ __launch_bounds__(256) void cast_state(const float* __restrict__ in,
                                                  ushort_t* __restrict__ hP) {
    int i = blockIdx.x * 256 + threadIdx.x;      // over BN*H/4
    float4 v = reinterpret_cast<const float4*>(in)[i];
    ushort4 h;
    h.x = __builtin_bit_cast(ushort_t, __float2half(v.x));
    h.y = __builtin_bit_cast(ushort_t, __float2half(v.y));
    h.z = __builtin_bit_cast(ushort_t, __float2half(v.z));
    h.w = __builtin_bit_cast(ushort_t, __float2half(v.w));
    reinterpret_cast<ushort4*>(hP)[i] = h;
}

// ---------------- weight fp16 transpose for edge MFMA (all layers) ----------------
// in: (4,T,H,H) = W[l][t][k][n]; out: (4,T,128,128) = [lt][n][kswz128(k,n)] fp16
__global__ void build_wt(const float* __restrict__ W, ushort_t* __restrict__ wt16) {
    int idx = blockIdx.x * 256 + threadIdx.x;
    if (idx >= 4 * T_ * H_ * H_) return;
    int lt = idx / (H_ * H_);
    int rem = idx - lt * H_ * H_;
    int n = rem >> 7, k = rem & 127;
    float v = W[(size_t)lt * H_ * H_ + k * H_ + n];
    size_t o = (size_t)lt * H_ * H_ + n * 128 + kswz128(k, n);
    wt16[o] = __builtin_bit_cast(ushort_t, __float2half(v));
}

// ---------------- B2 build: gate-interleaved padded GRU weights ----------------
// Row n' = cg*128 + gate*32 + c covers gate column j = cg*32 + c; every gate
// zero-padded to span [0,K). gate: 0=z 1=r 2=xh 3=hh.
struct BtArgs {
    const float* W[4];
    const float* U[4];
    unsigned long long off[4];
    int K[4];
};
__global__ void build_bt2(BtArgs a, ushort_t* __restrict__ bt16) {
    const int lyr = blockIdx.y;
    const int K = a.K[lyr];
    const int Kx = K - 128;
    int idx = blockIdx.x * 256 + threadIdx.x;
    if (idx >= 512 * K) return;
    int n = idx / K, k = idx - n * K;
    const int cg = n >> 7;
    const int gate = (n >> 5) & 3;
    const int j = cg * 32 + (n & 31);
    const float* W = a.W[lyr];
    const float* U = a.U[lyr];
    float v;
    if (gate == 0)      v = (k < Kx) ? W[(size_t)k * 384 + j] : U[(size_t)(k - Kx) * 384 + j];
    else if (gate == 1) v = (k < Kx) ? W[(size_t)k * 384 + 128 + j] : U[(size_t)(k - Kx) * 384 + 128 + j];
    else if (gate == 2) v = (k < Kx) ? W[(size_t)k * 384 + 256 + j] : 0.f;
    else                v = (k >= Kx) ? U[(size_t)(k - Kx) * 384 + 256 + j] : 0.f;
    size_t o = a.off[lyr] + (size_t)n * K + (size_t)(k & ~127) + kswz128(k & 127, n);
    bt16[o] = __builtin_bit_cast(ushort_t, __float2half(v));
}

// ---------------- edge message GEMM: single-shot K=128, fp16 MFMA ----------------
// Epilogue: C tile parked in Ah (dead after compute), then row-wise coalesced
// 16B stores (msg16 rows are 256B contiguous; scatter is only across rows).
__global__ __launch_bounds__(256) void edge_mfma(
    const ushort_t* __restrict__ hP,
    const int*   __restrict__ eids,
    const int*   __restrict__ perm,
    const int*   __restrict__ rank,
    const int*   __restrict__ meta,
    const ushort_t* __restrict__ wt16, // (T,128,128) [t][n][kswz128]
    const float* __restrict__ bias,    // (T,H)
    ushort_t*    __restrict__ msg16)   // (E,H) fp16, target-sorted
{
    __shared__ ushort_t Ah[EPB * 128];   // 16KB (A staging; reused for C tile)
    __shared__ ushort_t Bh[128 * 128];   // 32KB
    __shared__ int srcnode[EPB], outrow[EPB];
    const int tid = threadIdx.x;
    const int b = blockIdx.x;
    const int nb = meta[27 + T_];
    if (b >= nb) return;
    int t = 0;
    while (b >= meta[27 + t + 1]) t++;
    const int chunk = b - meta[27 + t];
    const int c0 = meta[t] - chunk * EPB;
    const int base = meta[9 + t] + chunk * EPB;
    const int cnt = (c0 > EPB) ? EPB : c0;

    if (tid < EPB) {
        int e = perm[base + ((tid < cnt) ? tid : 0)];
        srcnode[tid] = eids[e * 4 + 1] * N_ + eids[e * 4 + 2];
        outrow[tid]  = rank[e];
    }
    __syncthreads();

    const int w = tid >> 6, l = tid & 63;
    const int wr = (w >> 1) * 32, wc = (w & 1) * 64;
    const int l16 = l & 15, g = l >> 4;
    const int lr = l >> 4, s = l & 15;

    {
        const ushort_t* wrow = wt16 + (size_t)t * (128 * 128);
#pragma unroll
        for (int q = 0; q < 8; ++q) {
            const int n = w * 32 + q * 4 + lr;
            __builtin_amdgcn_global_load_lds(
                (const __attribute__((address_space(1))) void*)(wrow + (size_t)n * 128 + s * 8),
                (__attribute__((address_space(3))) void*)&Bh[(w * 32 + q * 4) * 128], 16, 0, 0);
        }
#pragma unroll
        for (int q = 0; q < 4; ++q) {
            const int row = w * 16 + q * 4 + lr;
            const int node = srcnode[row];
            __builtin_amdgcn_global_load_lds(
                (const __attribute__((address_space(1))) void*)(hP + (size_t)node * H_ + aslot_src(s, row)),
                (__attribute__((address_space(3))) void*)&Ah[(w * 16 + q * 4) * 128], 16, 0, 0);
        }
    }
    __syncthreads();

    f32x4 acc[2][4];
#pragma unroll
    for (int i = 0; i < 2; ++i)
#pragma unroll
        for (int j = 0; j < 4; ++j) acc[i][j] = (f32x4){0.f, 0.f, 0.f, 0.f};

#pragma unroll
    for (int kc = 0; kc < 4; ++kc) {
        f16x8 fah[2], fbh[4];
#pragma unroll
        for (int f = 0; f < 2; ++f)
            fah[f] = *reinterpret_cast<const f16x8*>(&Ah[ldoff(wr + f * 16 + l16, kc, g)]);
#pragma unroll
        for (int f = 0; f < 4; ++f)
            fbh[f] = *reinterpret_cast<const f16x8*>(&Bh[ldoff(wc + f * 16 + l16, kc, g)]);
#pragma unroll
        for (int mf = 0; mf < 2; ++mf)
#pragma unroll
            for (int nf = 0; nf < 4; ++nf)
                acc[mf][nf] = __builtin_amdgcn_mfma_f32_16x16x32_f16(fah[mf], fbh[nf], acc[mf][nf], 0, 0, 0);
    }

    // park C tile (+bias, fp16) into Ah[row][col] (linear 64x128)
    __syncthreads();   // all Ah reads done across waves
#pragma unroll
    for (int mf = 0; mf < 2; ++mf) {
        const int rbase = wr + mf * 16 + g * 4;
#pragma unroll
        for (int nf = 0; nf < 4; ++nf) {
            const int col = wc + nf * 16 + l16;
            const float bv = bias[t * H_ + col];
#pragma unroll
            for (int r = 0; r < 4; ++r)
                Ah[(rbase + r) * 128 + col] =
                    __builtin_bit_cast(ushort_t, __float2half(acc[mf][nf][r] + bv));
        }
    }
    __syncthreads();

    // coalesced store: 4 threads/row, 64B each (4 x 16B); rows 256B contiguous
    const int srow = tid >> 2, spart = tid & 3;
    if (srow < cnt) {
        const ushort_t* srcp = &Ah[srow * 128 + spart * 32];
        ushort_t* dstp = &msg16[(size_t)outrow[srow] * H_ + spart * 32];
#pragma unroll
        for (int q = 0; q < 4; ++q)
            reinterpret_cast<ushort8*>(dstp)[q] = reinterpret_cast<const ushort8*>(srcp)[q];
    }
}

// ---------------- segmented aggregation (fp16 in; fp16 plane out) ----------------
// 16 nodes/block; 16 lanes/node, 8 cols each (16B ushort8 loads, fully coalesced)
__global__ __launch_bounds__(256) void aggregate(
    const ushort_t* __restrict__ msg16,
    const int*      __restrict__ tstart,
    ushort_t*       __restrict__ agP)
{
    const int n  = blockIdx.x * 16 + (threadIdx.x >> 4);
    const int jc = (threadIdx.x & 15) * 8;
    const int s = tstart[n], e_end = tstart[n + 1];
    float a0 = 0.f, a1 = 0.f, a2 = 0.f, a3 = 0.f;
    float a4 = 0.f, a5 = 0.f, a6 = 0.f, a7 = 0.f;
    for (int i = s; i < e_end; ++i) {
        ushort8 u = *reinterpret_cast<const ushort8*>(&msg16[(size_t)i * H_ + jc]);
        a0 += __half2float(__builtin_bit_cast(__half, (ushort_t)u[0]));
        a1 += __half2float(__builtin_bit_cast(__half, (ushort_t)u[1]));
        a2 += __half2float(__builtin_bit_cast(__half, (ushort_t)u[2]));
        a3 += __half2float(__builtin_bit_cast(__half, (ushort_t)u[3]));
        a4 += __half2float(__builtin_bit_cast(__half, (ushort_t)u[4]));
        a5 += __half2float(__builtin_bit_cast(__half, (ushort_t)u[5]));
        a6 += __half2float(__builtin_bit_cast(__half, (ushort_t)u[6]));
        a7 += __half2float(__builtin_bit_cast(__half, (ushort_t)u[7]));
    }
    ushort8 h;
    h[0] = __builtin_bit_cast(ushort_t, __float2half(a0));
    h[1] = __builtin_bit_cast(ushort_t, __float2half(a1));
    h[2] = __builtin_bit_cast(ushort_t, __float2half(a2));
    h[3] = __builtin_bit_cast(ushort_t, __float2half(a3));
    h[4] = __builtin_bit_cast(ushort_t, __float2half(a4));
    h[5] = __builtin_bit_cast(ushort_t, __float2half(a5));
    h[6] = __builtin_bit_cast(ushort_t, __float2half(a6));
    h[7] = __builtin_bit_cast(ushort_t, __float2half(a7));
    *reinterpret_cast<ushort8*>(&agP[(size_t)n * H_ + jc]) = h;
}

// ---------------- fused gates GEMM + GRU nonlinearity ----------------
// Block (bx, cg): rows m0..m0+63, gate cols cg*32..cg*32+31 of ALL 4 gates.
// B tile rows n'' = gate*32 + c (128 rows x K, zero-padded per gate).
// Wave w = 16 M-rows x all 128 n''; lane holds z,r,xh,hh for its (row,col) pairs.
__global__ __launch_bounds__(256) void gru_mfma(
    const ushort_t* __restrict__ s0P, const ushort_t* __restrict__ s1P,
    const ushort_t* __restrict__ s2P, const ushort_t* __restrict__ s3P,
    const ushort_t* __restrict__ bt16,
    const int K,
    const float* __restrict__ hcur, const float* __restrict__ b,  // (2,384) flat
    float* __restrict__ hout, ushort_t* __restrict__ outP)
{
    __shared__ ushort_t Ah[64 * 128];    // 16KB
    __shared__ ushort_t Bh[128 * 128];   // 32KB
    const ushort_t* sP[4] = {s0P, s1P, s2P, s3P};
    const int tid = threadIdx.x;
    const int m0 = blockIdx.x * 64;
    const int cg = blockIdx.y;
    const int w = tid >> 6, l = tid & 63;
    const int l16 = l & 15, lg = l >> 4;
    const int lr = l >> 4, s = l & 15;

    f32x4 acc[8];
#pragma unroll
    for (int i = 0; i < 8; ++i) acc[i] = (f32x4){0.f, 0.f, 0.f, 0.f};

    for (int c = 0; c < K; c += 128) {
        if (c) __syncthreads();          // protect LDS before overwrite
        const ushort_t* sp = sP[c >> 7];
        // stage A: wave w rows w*16..+15 (4 instrs; per-lane pre-swizzled source)
#pragma unroll
        for (int q = 0; q < 4; ++q) {
            const int row = w * 16 + q * 4 + lr;
            __builtin_amdgcn_global_load_lds(
                (const __attribute__((address_space(1))) void*)(sp + (size_t)(m0 + row) * H_ + aslot_src(s, row)),
                (__attribute__((address_space(3))) void*)&Ah[(w * 16 + q * 4) * 128], 16, 0, 0);
        }
        // stage B: wave w rows w*32..+31 (8 instrs; swizzle baked in global layout)
#pragma unroll
        for (int q = 0; q < 8; ++q) {
            const int n = w * 32 + q * 4 + lr;
            __builtin_amdgcn_global_load_lds(
                (const __attribute__((address_space(1))) void*)(bt16 + (size_t)(cg * 128 + n) * K + c + s * 8),
                (__attribute__((address_space(3))) void*)&Bh[(w * 32 + q * 4) * 128], 16, 0, 0);
        }
        __syncthreads();
#pragma unroll
        for (int kc = 0; kc < 4; ++kc) {
            f16x8 fah = *reinterpret_cast<const f16x8*>(&Ah[ldoff(w * 16 + l16, kc, lg)]);
            f16x8 fbh[8];
#pragma unroll
            for (int nf = 0; nf < 8; ++nf)
                fbh[nf] = *reinterpret_cast<const f16x8*>(&Bh[ldoff(nf * 16 + l16, kc, lg)]);
#pragma unroll
            for (int nf = 0; nf < 8; ++nf)
                acc[nf] = __builtin_amdgcn_mfma_f32_16x16x32_f16(fah, fbh[nf], acc[nf], 0, 0, 0);
        }
    }

    // epilogue: lane holds z,r,xh,hh at nf = gate*2 + cpart, col c = cpart*16+l16.
    // C/D layout: col(n'') = nf*16 + l16, row = w*16 + lg*4 + reg.
#pragma unroll
    for (int cpart = 0; cpart < 2; ++cpart) {
        const int j = cg * 32 + cpart * 16 + l16;
        const float bz  = b[j] + b[384 + j];
        const float br  = b[128 + j] + b[512 + j];
        const float bxh = b[256 + j];
        const float bhh = b[640 + j];
#pragma unroll
        for (int r = 0; r < 4; ++r) {
            const int m = m0 + w * 16 + lg * 4 + r;
            const float zp = acc[cpart][r] + bz;
            const float rp = acc[2 + cpart][r] + br;
            const float xh = acc[4 + cpart][r] + bxh;
            const float hh = acc[6 + cpart][r] + bhh;
            const float z  = 1.f / (1.f + expf(-zp));
            const float rr = 1.f / (1.f + expf(-rp));
            const float cand = tanhf(xh + rr * hh);
            const float hv = hcur[(size_t)m * H_ + j];
            const float o = z * hv + (1.f - z) * cand;
            hout[(size_t)m * H_ + j] = o;
            outP[(size_t)m * H_ + j] = __builtin_bit_cast(ushort_t, __float2half(o));
        }
    }
}

// ---------------- host orchestration ----------------
extern "C" void kernel_launch(void* const* d_in, const int* in_sizes, int n_in,
                              void* d_out, int out_size, void* d_ws, size_t ws_size,
                              hipStream_t stream) {
    const float* states = (const float*)d_in[0];
    const int*   eids   = (const int*)  d_in[1];
    const float* tw     = (const float*)d_in[2];   // (4,T,H,H)
    const float* tb     = (const float*)d_in[3];   // (4,T,H)
    const float* gW[4]  = { (const float*)d_in[4],  (const float*)d_in[7],
                            (const float*)d_in[10], (const float*)d_in[13] };
    const float* gU[4]  = { (const float*)d_in[5],  (const float*)d_in[8],
                            (const float*)d_in[11], (const float*)d_in[14] };
    const float* gb[4]  = { (const float*)d_in[6],  (const float*)d_in[9],
                            (const float*)d_in[12], (const float*)d_in[15] };
    float* out = (float*)d_out;

    const int KL[4]   = {256, 384, 256, 512};              // IN_DIM + 128 per layer
    const size_t KOFF[4] = {0, 512ull*256, 512ull*(256+384), 512ull*(256+384+256)};
    const size_t BT_TOT  = 512ull * (256 + 384 + 256 + 512);   // 720896 ushorts
    const size_t WT_L    = (size_t)T_ * H_ * H_;               // per-layer W plane
    const size_t PL      = (size_t)BN_ * H_;                   // plane elems

    char* ws = (char*)d_ws;
    float* bufA = (float*)ws; ws += PL * 4;
    float* bufB = (float*)ws; ws += PL * 4;
    float* bufC = (float*)ws; ws += PL * 4;
    char*  msgR = ws;         ws += (size_t)E_ * H_ * 2;    // 33.5MB: msg16
    ushort_t* stP = (ushort_t*)ws; ws += PL * 2;
    ushort_t* paP = (ushort_t*)ws; ws += PL * 2;
    ushort_t* pbP = (ushort_t*)ws; ws += PL * 2;
    ushort_t* pcP = (ushort_t*)ws; ws += PL * 2;
    ushort_t* agP = (ushort_t*)ws; ws += PL * 2;
    ushort_t* btAll = (ushort_t*)ws; ws += BT_TOT * 2;
    ushort_t* wtAll = (ushort_t*)ws; ws += 4 * WT_L * 2;
    int*   perm  = (int*)ws;  ws += (size_t)E_ * 4;
    int*   rank  = (int*)ws;  ws += (size_t)E_ * 4;
    int*   tcnt  = (int*)ws;  ws += (size_t)BN_ * 4;
    int*   toff  = (int*)ws;  ws += (size_t)BN_ * 4;
    int*   tstart= (int*)ws;  ws += (size_t)(BN_ + 1) * 4;
    int*   meta  = (int*)ws;  ws += 64 * 4;
    ushort_t* msg16 = (ushort_t*)msgR;

    // ---- one-time sorts + casts (batched) ----
    hipMemsetAsync(meta, 0, 40 * sizeof(int), stream);
    hipMemsetAsync(tcnt, 0, BN_ * sizeof(int), stream);
    count_all<<<(E_ + 255) / 256, 256, 0, stream>>>(eids, meta, tcnt);
    scan_all  <<<1, 256, 0, stream>>>(tcnt, tstart, toff, meta);
    scatter_all<<<(E_ + 255) / 256, 256, 0, stream>>>(eids, meta, toff, perm, rank);
    cast_state<<<(int)(PL / 4 / 256), 256, 0, stream>>>(states, stP);

    BtArgs bta;
    for (int lyr = 0; lyr < 4; ++lyr) {
        bta.W[lyr] = gW[lyr]; bta.U[lyr] = gU[lyr];
        bta.off[lyr] = KOFF[lyr]; bta.K[lyr] = KL[lyr];
    }
    build_bt2<<<dim3((512 * 512 + 255) / 256, 4), 256, 0, stream>>>(bta, btAll);
    build_wt<<<(4 * (int)WT_L + 255) / 256, 256, 0, stream>>>(tw, wtAll);

    // step schedule: layers [0,0,0, 1, 2,2,2, 3]
    const int layer_of[8] = {0, 0, 0, 1, 2, 2, 2, 3};
    float*    target[8]  = {bufA, bufB, bufC, bufA, bufB, bufA, bufB, out};
    ushort_t* targetP[8] = {paP, pbP, pcP, paP, pbP, paP, pbP, paP};

    const float* cur = states;
    const ushort_t* curP = stP;
    const int edge_grid = E_ / EPB + T_;

    for (int s = 0; s < 8; ++s) {
        const int l = layer_of[s];
        edge_mfma<<<edge_grid, 256, 0, stream>>>(
            curP, eids, perm, rank, meta,
            wtAll + l * WT_L, tb + (size_t)l * T_ * H_, msg16);
        aggregate<<<BN_ / 16, 256, 0, stream>>>(msg16, tstart, agP);

        // A sources in order [res..., agg, cur]
        const ushort_t *p0, *p1, *p2, *p3;
        if (l == 0 || l == 2)      { p0 = agP; p1 = curP; p2 = nullptr; p3 = nullptr; }
        else if (l == 1)           { p0 = stP; p1 = agP;  p2 = curP;    p3 = nullptr; }
        else                       { p0 = stP; p1 = pcP;  p2 = agP;     p3 = curP;    }

        float* nxt = target[s];
        dim3 ggrid(BN_ / 64, 4);
        gru_mfma<<<ggrid, 256, 0, stream>>>(p0, p1, p2, p3,
                                            btAll + KOFF[l], KL[l],
                                            cur, gb[l], nxt, targetP[s]);
        cur = nxt; curP = targetP[s];
    }
}